// Round 19
// baseline (357.195 us; speedup 1.0000x reference)
//
#include <hip/hip_runtime.h>

#define B_ 512
#define T_ 256
#define F_ 8
#define H_ 128
#define BT_ (B_*T_)
#define MH_ 512
#define L2E 1.4426950408889634f

typedef __attribute__((ext_vector_type(4))) float f32x4;
typedef __attribute__((ext_vector_type(8))) __bf16 bf16x8;

// Static device scratch
// g_w2t: W2^T bf16, row n holds k-elems PRE-SWIZZLED: elem (k ^ ((n&7)<<3)).
__device__ unsigned short g_w2t[MH_*MH_];
// packed Whh/Wih bf16, [head][pc][k], PRE-SCALED: i,f,o rows by -log2e, g rows by +2log2e
__device__ unsigned short g_whh[3][512][128];
__device__ unsigned short g_wih[3][512][32];
__device__ unsigned short g_xbf[3][B_*T_*F_];        // x in bf16, same (B,T,F) layout

__device__ __forceinline__ unsigned short f2bf(float f){
  unsigned int u = __float_as_uint(f);
  unsigned int r = (u + 0x7FFFu + ((u >> 16) & 1u)) >> 16;  // RNE
  return (unsigned short)r;
}

#if __has_builtin(__builtin_amdgcn_exp2f)
#define EXP2F __builtin_amdgcn_exp2f
#else
#define EXP2F exp2f
#endif
#define RCPF __builtin_amdgcn_rcpf

// DPP-based partial-sum step on the VALU pipe (verified +46us in r12).
template<int CTRL>
__device__ __forceinline__ float dpp_sum_step(float v){
  int t = __builtin_amdgcn_update_dpp(0, __float_as_int(v), CTRL, 0xF, 0xF, true);
  return v + __int_as_float(t);
}

// lgkm-only barrier (measured neutral vs __syncthreads in r17; kept as part
// of the verified-best base).
__device__ __forceinline__ void bar_lgkm(){
  asm volatile("s_waitcnt lgkmcnt(0)\n\ts_barrier" ::: "memory");
}

struct LstmArgs {
  const float* x[3];
  const float* Wih[3];
  const float* Whh[3];
  const float* bias[3];
  const float* hw[3];
  const float* hb[3];
  float* out;
};

// One fused prep: W2^T pack (pre-swizzled) + Whh/Wih MFMA-order pack
// (pre-scaled by +-log2e) + x to bf16.  (verified)
__global__ __launch_bounds__(256) void prep_all(LstmArgs A, const float* __restrict__ W2){
  const int NW2 = MH_*MH_;
  const int NW  = 3*512*128;
  const int NI  = 3*512*32;
  const int NX  = 3*B_*T_*F_;
  const int TOT = NW2 + NW + NI + NX;
  for (int i = blockIdx.x*256 + threadIdx.x; i < TOT; i += gridDim.x*256){
    if (i < NW2){
      int n = i >> 9;
      int k = i & 511;
      g_w2t[(n << 9) | (k ^ ((n & 7) << 3))] = f2bf(W2[(size_t)k * MH_ + n]);
    } else if (i < NW2 + NW){
      int j = i - NW2;
      int head = j >> 16;
      int r = j & 65535;
      int pc = r >> 7, k = r & 127;
      int w = pc >> 6, g = (pc >> 4) & 3, s = pc & 15;
      int row = g*128 + w*16 + s;
      float sc = (g == 2) ? (2.0f*L2E) : (-L2E);
      g_whh[head][pc][k] = f2bf(A.Whh[head][row*H_ + k] * sc);
    } else if (i < NW2 + NW + NI){
      int j = i - NW2 - NW;
      int head = j >> 14;
      int r = j & 16383;
      int pc = r >> 5, k = r & 31;
      int w = pc >> 6, g = (pc >> 4) & 3, s = pc & 15;
      int row = g*128 + w*16 + s;
      float sc = (g == 2) ? (2.0f*L2E) : (-L2E);
      g_wih[head][pc][k] = (k < 8) ? f2bf(A.Wih[head][row*F_ + k] * sc) : (unsigned short)0;
    } else {
      int j = i - NW2 - NW - NI;
      int head = j >> 20;
      int r = j & 1048575;
      g_xbf[head][r] = f2bf(A.x[head][r]);
    }
  }
}

// MFMA LSTM — r18 verified best (213us), unchanged.
//  8-batch row-spread tiles, 192 blocks, 2 cells/lane, parallel exp2 gates,
//  min-depth MFMA chains (x starts chain A under the ds_read), DPP head-dot
//  one step late, wave-0 finalize, lgkm-only barrier, h double-buffered.
__global__ __launch_bounds__(512) void lstm_mfma_kernel(LstmArgs A){
  const int head   = blockIdx.x >> 6;          // 64 tiles per head, 192 blocks
  const int batch0 = (blockIdx.x & 63) * 8;
  const int tid = threadIdx.x;
  const int w   = tid >> 6;
  const int l   = tid & 63;
  const int c16 = l & 15;
  const int kb  = (l >> 4) * 8;

  const float* __restrict__ bs  = A.bias[head];
  const float* __restrict__ hwp = A.hw[head];
  const float hbv = A.hb[head][0];
  float* __restrict__ D = A.out + (size_t)head * BT_;

  // register-resident B-fragments
  bf16x8 bh[4][4];
  bf16x8 bx[4];
  #pragma unroll
  for (int g = 0; g < 4; ++g){
    const int pc = w*64 + g*16 + c16;
    #pragma unroll
    for (int kk = 0; kk < 4; ++kk)
      bh[g][kk] = *(const bf16x8*)&g_whh[head][pc][kk*32 + kb];
    bx[g] = *(const bf16x8*)&g_wih[head][pc][kb];
  }

  const int u = w*16 + c16;
  const float bi_ = bs[u]        * (-L2E);
  const float bf_ = bs[H_+u]     * (-L2E);
  const float bg_ = bs[2*H_+u]   * (2.0f*L2E);
  const float bo_ = bs[3*H_+u]   * (-L2E);
  const float hw_u = hwp[u];

  __shared__ __align__(16) unsigned short h_bf[2][16][132];
  __shared__ float part[2][8][8];

  for (int i = tid; i < 2*16*132; i += 512) ((unsigned short*)h_bf)[i] = 0;

  float cst[2] = {0.f, 0.f};
  float pp[2]  = {0.f, 0.f};

  // x A-row mapping: lane c16 supplies A-row c16; valid rows {0,1,4,5,8,9,12,13}
  const int bt = ((c16 >> 2) << 1) | (c16 & 1);          // batch-in-tile for row c16
  const bool xvalid = (l < 16) && !(l & 2);
  const unsigned short* __restrict__ xrow =
      &g_xbf[head][(size_t)(batch0 + bt) * (T_*F_)];

  bf16x8 ax_cur = {};
  if (xvalid) ax_cur = *(const bf16x8*)(xrow);

  __syncthreads();

  int cur = 0;
  for (int ts = 0; ts < T_; ++ts){
    // A-frags for current h
    bf16x8 ah[4];
    #pragma unroll
    for (int kk = 0; kk < 4; ++kk)
      ah[kk] = *(const bf16x8*)&h_bf[cur][c16][kk*32 + kb];

    // prefetch next step's x (off the critical path; stays in flight)
    bf16x8 ax_nxt = {};
    {
      const int tn = (ts + 1 < T_) ? ts + 1 : ts;
      if (xvalid) ax_nxt = *(const bf16x8*)(xrow + tn*F_);
    }

    // minimum-depth MFMA chains:
    //   chain A (acc):  x-MFMA (indep of ds_read) -> ah0 -> ah1
    //   chain B (acc2): ah2 -> ah3
    f32x4 acc[4], acc2[4];
    const f32x4 z4 = {0.f, 0.f, 0.f, 0.f};
    #pragma unroll
    for (int g = 0; g < 4; ++g)
      acc[g]  = __builtin_amdgcn_mfma_f32_16x16x32_bf16(ax_cur, bx[g], z4, 0, 0, 0);
    #pragma unroll
    for (int g = 0; g < 4; ++g)
      acc2[g] = __builtin_amdgcn_mfma_f32_16x16x32_bf16(ah[2], bh[g][2], z4, 0, 0, 0);
    #pragma unroll
    for (int g = 0; g < 4; ++g)
      acc[g]  = __builtin_amdgcn_mfma_f32_16x16x32_bf16(ah[0], bh[g][0], acc[g], 0, 0, 0);
    #pragma unroll
    for (int g = 0; g < 4; ++g)
      acc2[g] = __builtin_amdgcn_mfma_f32_16x16x32_bf16(ah[3], bh[g][3], acc2[g], 0, 0, 0);
    #pragma unroll
    for (int g = 0; g < 4; ++g)
      acc[g]  = __builtin_amdgcn_mfma_f32_16x16x32_bf16(ah[1], bh[g][1], acc[g], 0, 0, 0);

    // previous step's head-dot reduction (DPP on VALU; overlaps MFMA)
    if (ts > 0){
      #pragma unroll
      for (int r = 0; r < 2; ++r){
        float v = pp[r];
        v = dpp_sum_step<0xB1>(v);    // ~xor1
        v = dpp_sum_step<0x4E>(v);    // ~xor2
        v = dpp_sum_step<0x141>(v);   // half-mirror (complementary quads)
        v = dpp_sum_step<0x140>(v);   // mirror (complementary octets)
        if (c16 == 0) part[(ts-1) & 1][(l >> 4)*2 + r][w] = v;
      }
    }

    // cell update: 2 cells/lane (regs r=0,1), PARALLEL exp2-form gates
    #pragma unroll
    for (int r = 0; r < 2; ++r){
      const float Zi = (acc[0][r] + acc2[0][r]) + bi_;
      const float Zf = (acc[1][r] + acc2[1][r]) + bf_;
      const float Zg = (acc[2][r] + acc2[2][r]) + bg_;
      const float Zo = (acc[3][r] + acc2[3][r]) + bo_;
      const float si = RCPF(1.f + EXP2F(Zi));
      const float sf = RCPF(1.f + EXP2F(Zf));
      const float tg = 1.f - 2.f * RCPF(EXP2F(Zg) + 1.f);
      const float so = RCPF(1.f + EXP2F(Zo));
      cst[r] = sf * cst[r] + si * tg;
      const float tc = 1.f - 2.f * RCPF(EXP2F(cst[r] * (2.0f*L2E)) + 1.f);
      const float hnr = so * tc;
      h_bf[cur ^ 1][(l >> 4)*4 + r][u] = f2bf(hnr);
      pp[r] = hnr * hw_u;                       // consumed next iteration
    }

    bar_lgkm();                                 // new h + part visible (lgkm only)

    // finalize D for step ts-1 (wave 0 only; overlaps other waves' next step)
    if (ts > 0 && tid < 64){
      const int b  = tid >> 3;
      const int wv = tid & 7;
      float v = part[(ts-1) & 1][b][wv];
      v = dpp_sum_step<0xB1>(v);
      v = dpp_sum_step<0x4E>(v);
      v = dpp_sum_step<0x141>(v);
      if (wv == 0) D[(size_t)(batch0 + b) * T_ + (ts-1)] = v + hbv;
    }

    ax_cur = ax_nxt;
    cur ^= 1;
  }

  // epilogue: step T-1's head-dot
  #pragma unroll
  for (int r = 0; r < 2; ++r){
    float v = pp[r];
    v = dpp_sum_step<0xB1>(v);
    v = dpp_sum_step<0x4E>(v);
    v = dpp_sum_step<0x141>(v);
    v = dpp_sum_step<0x140>(v);
    if (c16 == 0) part[(T_-1) & 1][(l >> 4)*2 + r][w] = v;
  }
  __syncthreads();
  if (tid < 64){
    const int b  = tid >> 3;
    const int wv = tid & 7;
    float v = part[(T_-1) & 1][b][wv];
    v = dpp_sum_step<0xB1>(v);
    v = dpp_sum_step<0x4E>(v);
    v = dpp_sum_step<0x141>(v);
    if (wv == 0) D[(size_t)(batch0 + b) * T_ + (T_-1)] = v + hbv;
  }
}

// Fused MLP v5: mt=3 (48 rows/wave) to cut B-operand LDS traffic by 1/3.
// Each wave reads all of W2 (512KB) over its 16 passes, so chip LDS-read
// volume = waves * 512KB; waves drop 4096 -> 2736 (2GB -> 1.37GB).
// 342 blocks x 512 threads (8 waves), 384 rows/block, tail block guarded.
// afr[3][16] = 192 reg-equivalents: unified VGPR/AGPR file absorbs it at
// launch_bounds(512,1) (cap 256 VGPR + AGPR headroom; r10 precedent).
__global__ __launch_bounds__(512, 1) void mlp_kernel(
    const float* __restrict__ Dbase,
    const float* __restrict__ W1, const float* __restrict__ b1,
    const float* __restrict__ b2, const float* __restrict__ W3,
    const float* __restrict__ b3, float* __restrict__ out)
{
  __shared__ __align__(16) unsigned short buf[2][32*512];   // 2 x 32KB

  const int tid = threadIdx.x;
  const int l   = tid & 63;
  const int c16 = l & 15;
  const int kb  = (l >> 4) * 8;
  const int w   = tid >> 6;                 // 0..7
  const int m0  = blockIdx.x * 384 + w * 48;

  // A fragments for 3 M-tiles (computed once; live for whole kernel)
  bf16x8 afr[3][16];
  {
    float d[3][3];
    #pragma unroll
    for (int mt = 0; mt < 3; ++mt){
      int gr = m0 + mt*16 + c16;
      if (gr >= BT_) gr = BT_ - 1;         // tail clamp (values unused on store)
      d[mt][0] = Dbase[gr];
      d[mt][1] = Dbase[BT_ + gr];
      d[mt][2] = Dbase[2*BT_ + gr];
    }
    #pragma unroll
    for (int ks = 0; ks < 16; ++ks){
      const int kg = ks*32 + kb;
      const f32x4 wa0 = *(const f32x4*)(W1 + kg);          const f32x4 wa1 = *(const f32x4*)(W1 + kg + 4);
      const f32x4 wb0 = *(const f32x4*)(W1 + MH_ + kg);    const f32x4 wb1 = *(const f32x4*)(W1 + MH_ + kg + 4);
      const f32x4 wc0 = *(const f32x4*)(W1 + 2*MH_ + kg);  const f32x4 wc1 = *(const f32x4*)(W1 + 2*MH_ + kg + 4);
      const f32x4 bv0 = *(const f32x4*)(b1 + kg);          const f32x4 bv1 = *(const f32x4*)(b1 + kg + 4);
      #pragma unroll
      for (int mt = 0; mt < 3; ++mt){
        union { unsigned short us[8]; bf16x8 v; } au;
        #pragma unroll
        for (int i = 0; i < 4; ++i){
          float v0 = fmaf(d[mt][2], wc0[i], fmaf(d[mt][1], wb0[i], fmaf(d[mt][0], wa0[i], bv0[i])));
          float v1 = fmaf(d[mt][2], wc1[i], fmaf(d[mt][1], wb1[i], fmaf(d[mt][0], wa1[i], bv1[i])));
          au.us[i]     = f2bf(fmaxf(v0, 0.f));
          au.us[4 + i] = f2bf(fmaxf(v1, 0.f));
        }
        afr[mt][ks] = au.v;
      }
    }
  }

  // prologue: stage regs for pass 0 (pass = 32 cols = 2048 uint4; 4/thread)
  const uint4* __restrict__ gsrc = (const uint4*)g_w2t;
  uint4 rg0, rg1, rg2, rg3;
  {
    const uint4* s = gsrc + tid;
    rg0 = s[0*512]; rg1 = s[1*512]; rg2 = s[2*512]; rg3 = s[3*512];
  }

  float rs[3][4] = {{0.f,0.f,0.f,0.f},{0.f,0.f,0.f,0.f},{0.f,0.f,0.f,0.f}};

  #pragma unroll 1
  for (int p = 0; p < 16; ++p){
    {
      uint4* bw = (uint4*)buf[p & 1] + tid;
      bw[0*512] = rg0; bw[1*512] = rg1; bw[2*512] = rg2; bw[3*512] = rg3;
    }
    __syncthreads();               // write visible; dbuf makes this the ONLY barrier
    if (p < 15){
      const uint4* s = gsrc + (p + 1) * 2048 + tid;
      rg0 = s[0*512]; rg1 = s[1*512]; rg2 = s[2*512]; rg3 = s[3*512];
    }
    float b2v[2], w3v[2];
    #pragma unroll
    for (int nt = 0; nt < 2; ++nt){
      const int n = p*32 + nt*16 + c16;
      b2v[nt] = b2[n];
      w3v[nt] = W3[n];
    }

    const unsigned short* __restrict__ bb = buf[p & 1];
    f32x4 acc[3][2];
    #pragma unroll
    for (int nt = 0; nt < 2; ++nt){
      f32x4 z = {0.f,0.f,0.f,0.f};
      acc[0][nt] = z; acc[1][nt] = z; acc[2][nt] = z;
    }
    #pragma unroll
    for (int ks = 0; ks < 16; ++ks){
      #pragma unroll
      for (int nt = 0; nt < 2; ++nt){
        const int nl = nt*16 + c16;                    // local col 0..31
        const bf16x8 bfr =
          *(const bf16x8*)&bb[(nl << 9) | ((ks*32 + kb) ^ ((nl & 7) << 3))];
        acc[0][nt] = __builtin_amdgcn_mfma_f32_16x16x32_bf16(afr[0][ks], bfr, acc[0][nt], 0, 0, 0);
        acc[1][nt] = __builtin_amdgcn_mfma_f32_16x16x32_bf16(afr[1][ks], bfr, acc[1][nt], 0, 0, 0);
        acc[2][nt] = __builtin_amdgcn_mfma_f32_16x16x32_bf16(afr[2][ks], bfr, acc[2][nt], 0, 0, 0);
      }
    }
    #pragma unroll
    for (int nt = 0; nt < 2; ++nt){
      #pragma unroll
      for (int mt = 0; mt < 3; ++mt)
        #pragma unroll
        for (int r = 0; r < 4; ++r)
          rs[mt][r] += fmaxf(acc[mt][nt][r] + b2v[nt], 0.f) * w3v[nt];
    }
  }

  // reduce across the 16 lanes (c16 bits) sharing the same C-rows
  #pragma unroll
  for (int mt = 0; mt < 3; ++mt){
    #pragma unroll
    for (int r = 0; r < 4; ++r){
      rs[mt][r] += __shfl_xor(rs[mt][r], 1);
      rs[mt][r] += __shfl_xor(rs[mt][r], 2);
      rs[mt][r] += __shfl_xor(rs[mt][r], 4);
      rs[mt][r] += __shfl_xor(rs[mt][r], 8);
    }
  }
  if (c16 == 0){
    const float bv = b3[0];
    #pragma unroll
    for (int mt = 0; mt < 3; ++mt){
      const int row = m0 + mt*16 + (l >> 4) * 4;
      if (row < BT_){                         // tail guard (row%4==0 => row+3 ok)
        #pragma unroll
        for (int r = 0; r < 4; ++r)
          out[3*BT_ + row + r] = rs[mt][r] + bv;
      }
    }
  }
}

extern "C" void kernel_launch(void* const* d_in, const int* in_sizes, int n_in,
                              void* d_out, int out_size, void* d_ws, size_t ws_size,
                              hipStream_t stream){
  LstmArgs A;
  for (int i = 0; i < 3; ++i){
    A.x[i]    = (const float*)d_in[i];
    A.Wih[i]  = (const float*)d_in[3 + i*5 + 0];
    A.Whh[i]  = (const float*)d_in[3 + i*5 + 1];
    A.bias[i] = (const float*)d_in[3 + i*5 + 2];
    A.hw[i]   = (const float*)d_in[3 + i*5 + 3];
    A.hb[i]   = (const float*)d_in[3 + i*5 + 4];
  }
  A.out = (float*)d_out;

  prep_all<<<dim3(2048), dim3(256), 0, stream>>>(A, (const float*)d_in[20]);
  lstm_mfma_kernel<<<dim3(192), dim3(512), 0, stream>>>(A);
  mlp_kernel<<<dim3(342), dim3(512), 0, stream>>>((const float*)d_out,
      (const float*)d_in[18], (const float*)d_in[19],
      (const float*)d_in[21], (const float*)d_in[22], (const float*)d_in[23],
      (float*)d_out);
}

// Round 20
// 275.821 us; speedup vs baseline: 1.2950x; 1.2950x over previous
//
#include <hip/hip_runtime.h>

#define B_ 512
#define T_ 256
#define F_ 8
#define H_ 128
#define BT_ (B_*T_)
#define MH_ 512
#define L2E 1.4426950408889634f

typedef __attribute__((ext_vector_type(4))) float f32x4;
typedef __attribute__((ext_vector_type(8))) __bf16 bf16x8;

// Static device scratch
// g_w2t: W2^T bf16, row n holds k-elems PRE-SWIZZLED: elem (k ^ ((n&7)<<3)).
__device__ unsigned short g_w2t[MH_*MH_];
// packed Whh/Wih bf16, [head][pc][k], PRE-SCALED: i,f,o rows by -log2e, g rows by +2log2e
__device__ unsigned short g_whh[3][512][128];
__device__ unsigned short g_wih[3][512][32];
__device__ unsigned short g_xbf[3][B_*T_*F_];        // x in bf16, same (B,T,F) layout

__device__ __forceinline__ unsigned short f2bf(float f){
  unsigned int u = __float_as_uint(f);
  unsigned int r = (u + 0x7FFFu + ((u >> 16) & 1u)) >> 16;  // RNE
  return (unsigned short)r;
}

#if __has_builtin(__builtin_amdgcn_exp2f)
#define EXP2F __builtin_amdgcn_exp2f
#else
#define EXP2F exp2f
#endif
#define RCPF __builtin_amdgcn_rcpf

// DPP-based partial-sum step on the VALU pipe (verified +46us in r12).
template<int CTRL>
__device__ __forceinline__ float dpp_sum_step(float v){
  int t = __builtin_amdgcn_update_dpp(0, __float_as_int(v), CTRL, 0xF, 0xF, true);
  return v + __int_as_float(t);
}

// lgkm-only barrier (measured neutral vs __syncthreads in r17; kept as part
// of the verified-best base).
__device__ __forceinline__ void bar_lgkm(){
  asm volatile("s_waitcnt lgkmcnt(0)\n\ts_barrier" ::: "memory");
}

struct LstmArgs {
  const float* x[3];
  const float* Wih[3];
  const float* Whh[3];
  const float* bias[3];
  const float* hw[3];
  const float* hb[3];
  float* out;
};

// One fused prep: W2^T pack (pre-swizzled) + Whh/Wih MFMA-order pack
// (pre-scaled by +-log2e) + x to bf16.  (verified)
__global__ __launch_bounds__(256) void prep_all(LstmArgs A, const float* __restrict__ W2){
  const int NW2 = MH_*MH_;
  const int NW  = 3*512*128;
  const int NI  = 3*512*32;
  const int NX  = 3*B_*T_*F_;
  const int TOT = NW2 + NW + NI + NX;
  for (int i = blockIdx.x*256 + threadIdx.x; i < TOT; i += gridDim.x*256){
    if (i < NW2){
      int n = i >> 9;
      int k = i & 511;
      g_w2t[(n << 9) | (k ^ ((n & 7) << 3))] = f2bf(W2[(size_t)k * MH_ + n]);
    } else if (i < NW2 + NW){
      int j = i - NW2;
      int head = j >> 16;
      int r = j & 65535;
      int pc = r >> 7, k = r & 127;
      int w = pc >> 6, g = (pc >> 4) & 3, s = pc & 15;
      int row = g*128 + w*16 + s;
      float sc = (g == 2) ? (2.0f*L2E) : (-L2E);
      g_whh[head][pc][k] = f2bf(A.Whh[head][row*H_ + k] * sc);
    } else if (i < NW2 + NW + NI){
      int j = i - NW2 - NW;
      int head = j >> 14;
      int r = j & 16383;
      int pc = r >> 5, k = r & 31;
      int w = pc >> 6, g = (pc >> 4) & 3, s = pc & 15;
      int row = g*128 + w*16 + s;
      float sc = (g == 2) ? (2.0f*L2E) : (-L2E);
      g_wih[head][pc][k] = (k < 8) ? f2bf(A.Wih[head][row*F_ + k] * sc) : (unsigned short)0;
    } else {
      int j = i - NW2 - NW - NI;
      int head = j >> 20;
      int r = j & 1048575;
      g_xbf[head][r] = f2bf(A.x[head][r]);
    }
  }
}

// MFMA LSTM — r18 verified best (213us), unchanged.
//  8-batch row-spread tiles, 192 blocks, 2 cells/lane, parallel exp2 gates,
//  min-depth MFMA chains (x starts chain A under the ds_read), DPP head-dot
//  one step late, wave-0 finalize, lgkm-only barrier, h double-buffered.
__global__ __launch_bounds__(512) void lstm_mfma_kernel(LstmArgs A){
  const int head   = blockIdx.x >> 6;          // 64 tiles per head, 192 blocks
  const int batch0 = (blockIdx.x & 63) * 8;
  const int tid = threadIdx.x;
  const int w   = tid >> 6;
  const int l   = tid & 63;
  const int c16 = l & 15;
  const int kb  = (l >> 4) * 8;

  const float* __restrict__ bs  = A.bias[head];
  const float* __restrict__ hwp = A.hw[head];
  const float hbv = A.hb[head][0];
  float* __restrict__ D = A.out + (size_t)head * BT_;

  // register-resident B-fragments
  bf16x8 bh[4][4];
  bf16x8 bx[4];
  #pragma unroll
  for (int g = 0; g < 4; ++g){
    const int pc = w*64 + g*16 + c16;
    #pragma unroll
    for (int kk = 0; kk < 4; ++kk)
      bh[g][kk] = *(const bf16x8*)&g_whh[head][pc][kk*32 + kb];
    bx[g] = *(const bf16x8*)&g_wih[head][pc][kb];
  }

  const int u = w*16 + c16;
  const float bi_ = bs[u]        * (-L2E);
  const float bf_ = bs[H_+u]     * (-L2E);
  const float bg_ = bs[2*H_+u]   * (2.0f*L2E);
  const float bo_ = bs[3*H_+u]   * (-L2E);
  const float hw_u = hwp[u];

  __shared__ __align__(16) unsigned short h_bf[2][16][132];
  __shared__ float part[2][8][8];

  for (int i = tid; i < 2*16*132; i += 512) ((unsigned short*)h_bf)[i] = 0;

  float cst[2] = {0.f, 0.f};
  float pp[2]  = {0.f, 0.f};

  // x A-row mapping: lane c16 supplies A-row c16; valid rows {0,1,4,5,8,9,12,13}
  const int bt = ((c16 >> 2) << 1) | (c16 & 1);          // batch-in-tile for row c16
  const bool xvalid = (l < 16) && !(l & 2);
  const unsigned short* __restrict__ xrow =
      &g_xbf[head][(size_t)(batch0 + bt) * (T_*F_)];

  bf16x8 ax_cur = {};
  if (xvalid) ax_cur = *(const bf16x8*)(xrow);

  __syncthreads();

  int cur = 0;
  for (int ts = 0; ts < T_; ++ts){
    // A-frags for current h
    bf16x8 ah[4];
    #pragma unroll
    for (int kk = 0; kk < 4; ++kk)
      ah[kk] = *(const bf16x8*)&h_bf[cur][c16][kk*32 + kb];

    // prefetch next step's x (off the critical path; stays in flight)
    bf16x8 ax_nxt = {};
    {
      const int tn = (ts + 1 < T_) ? ts + 1 : ts;
      if (xvalid) ax_nxt = *(const bf16x8*)(xrow + tn*F_);
    }

    // minimum-depth MFMA chains:
    //   chain A (acc):  x-MFMA (indep of ds_read) -> ah0 -> ah1
    //   chain B (acc2): ah2 -> ah3
    f32x4 acc[4], acc2[4];
    const f32x4 z4 = {0.f, 0.f, 0.f, 0.f};
    #pragma unroll
    for (int g = 0; g < 4; ++g)
      acc[g]  = __builtin_amdgcn_mfma_f32_16x16x32_bf16(ax_cur, bx[g], z4, 0, 0, 0);
    #pragma unroll
    for (int g = 0; g < 4; ++g)
      acc2[g] = __builtin_amdgcn_mfma_f32_16x16x32_bf16(ah[2], bh[g][2], z4, 0, 0, 0);
    #pragma unroll
    for (int g = 0; g < 4; ++g)
      acc[g]  = __builtin_amdgcn_mfma_f32_16x16x32_bf16(ah[0], bh[g][0], acc[g], 0, 0, 0);
    #pragma unroll
    for (int g = 0; g < 4; ++g)
      acc2[g] = __builtin_amdgcn_mfma_f32_16x16x32_bf16(ah[3], bh[g][3], acc2[g], 0, 0, 0);
    #pragma unroll
    for (int g = 0; g < 4; ++g)
      acc[g]  = __builtin_amdgcn_mfma_f32_16x16x32_bf16(ah[1], bh[g][1], acc[g], 0, 0, 0);

    // previous step's head-dot reduction (DPP on VALU; overlaps MFMA)
    if (ts > 0){
      #pragma unroll
      for (int r = 0; r < 2; ++r){
        float v = pp[r];
        v = dpp_sum_step<0xB1>(v);    // ~xor1
        v = dpp_sum_step<0x4E>(v);    // ~xor2
        v = dpp_sum_step<0x141>(v);   // half-mirror (complementary quads)
        v = dpp_sum_step<0x140>(v);   // mirror (complementary octets)
        if (c16 == 0) part[(ts-1) & 1][(l >> 4)*2 + r][w] = v;
      }
    }

    // cell update: 2 cells/lane (regs r=0,1), PARALLEL exp2-form gates
    #pragma unroll
    for (int r = 0; r < 2; ++r){
      const float Zi = (acc[0][r] + acc2[0][r]) + bi_;
      const float Zf = (acc[1][r] + acc2[1][r]) + bf_;
      const float Zg = (acc[2][r] + acc2[2][r]) + bg_;
      const float Zo = (acc[3][r] + acc2[3][r]) + bo_;
      const float si = RCPF(1.f + EXP2F(Zi));
      const float sf = RCPF(1.f + EXP2F(Zf));
      const float tg = 1.f - 2.f * RCPF(EXP2F(Zg) + 1.f);
      const float so = RCPF(1.f + EXP2F(Zo));
      cst[r] = sf * cst[r] + si * tg;
      const float tc = 1.f - 2.f * RCPF(EXP2F(cst[r] * (2.0f*L2E)) + 1.f);
      const float hnr = so * tc;
      h_bf[cur ^ 1][(l >> 4)*4 + r][u] = f2bf(hnr);
      pp[r] = hnr * hw_u;                       // consumed next iteration
    }

    bar_lgkm();                                 // new h + part visible (lgkm only)

    // finalize D for step ts-1 (wave 0 only; overlaps other waves' next step)
    if (ts > 0 && tid < 64){
      const int b  = tid >> 3;
      const int wv = tid & 7;
      float v = part[(ts-1) & 1][b][wv];
      v = dpp_sum_step<0xB1>(v);
      v = dpp_sum_step<0x4E>(v);
      v = dpp_sum_step<0x141>(v);
      if (wv == 0) D[(size_t)(batch0 + b) * T_ + (ts-1)] = v + hbv;
    }

    ax_cur = ax_nxt;
    cur ^= 1;
  }

  // epilogue: step T-1's head-dot
  #pragma unroll
  for (int r = 0; r < 2; ++r){
    float v = pp[r];
    v = dpp_sum_step<0xB1>(v);
    v = dpp_sum_step<0x4E>(v);
    v = dpp_sum_step<0x141>(v);
    v = dpp_sum_step<0x140>(v);
    if (c16 == 0) part[(T_-1) & 1][(l >> 4)*2 + r][w] = v;
  }
  __syncthreads();
  if (tid < 64){
    const int b  = tid >> 3;
    const int wv = tid & 7;
    float v = part[(T_-1) & 1][b][wv];
    v = dpp_sum_step<0xB1>(v);
    v = dpp_sum_step<0x4E>(v);
    v = dpp_sum_step<0x141>(v);
    if (wv == 0) D[(size_t)(batch0 + b) * T_ + (T_-1)] = v + hbv;
  }
}

// Fused MLP v4 (r17/r18 verified ~47us): 512 blocks x 512 threads (8 waves),
// 256 rows/block, mt=2; each staged W2 pass serves 8 waves.
// launch_bounds(512,1): VGPR cap 256 (mt=3 spills/collapses — r19 lesson;
// (512,2) caps at 128 and spills afr — r8/r9 lesson).
__global__ __launch_bounds__(512, 1) void mlp_kernel(
    const float* __restrict__ Dbase,
    const float* __restrict__ W1, const float* __restrict__ b1,
    const float* __restrict__ b2, const float* __restrict__ W3,
    const float* __restrict__ b3, float* __restrict__ out)
{
  __shared__ __align__(16) unsigned short buf[2][32*512];   // 2 x 32KB

  const int tid = threadIdx.x;
  const int l   = tid & 63;
  const int c16 = l & 15;
  const int kb  = (l >> 4) * 8;
  const int w   = tid >> 6;                 // 0..7
  const int m0  = blockIdx.x * 256 + w * 32;

  // A fragments for 2 M-tiles (computed once; live for whole kernel)
  bf16x8 afr[2][16];
  {
    float d[2][3];
    #pragma unroll
    for (int mt = 0; mt < 2; ++mt){
      const int gr = m0 + mt*16 + c16;
      d[mt][0] = Dbase[gr];
      d[mt][1] = Dbase[BT_ + gr];
      d[mt][2] = Dbase[2*BT_ + gr];
    }
    #pragma unroll
    for (int ks = 0; ks < 16; ++ks){
      const int kg = ks*32 + kb;
      const f32x4 wa0 = *(const f32x4*)(W1 + kg);          const f32x4 wa1 = *(const f32x4*)(W1 + kg + 4);
      const f32x4 wb0 = *(const f32x4*)(W1 + MH_ + kg);    const f32x4 wb1 = *(const f32x4*)(W1 + MH_ + kg + 4);
      const f32x4 wc0 = *(const f32x4*)(W1 + 2*MH_ + kg);  const f32x4 wc1 = *(const f32x4*)(W1 + 2*MH_ + kg + 4);
      const f32x4 bv0 = *(const f32x4*)(b1 + kg);          const f32x4 bv1 = *(const f32x4*)(b1 + kg + 4);
      #pragma unroll
      for (int mt = 0; mt < 2; ++mt){
        union { unsigned short us[8]; bf16x8 v; } au;
        #pragma unroll
        for (int i = 0; i < 4; ++i){
          float v0 = fmaf(d[mt][2], wc0[i], fmaf(d[mt][1], wb0[i], fmaf(d[mt][0], wa0[i], bv0[i])));
          float v1 = fmaf(d[mt][2], wc1[i], fmaf(d[mt][1], wb1[i], fmaf(d[mt][0], wa1[i], bv1[i])));
          au.us[i]     = f2bf(fmaxf(v0, 0.f));
          au.us[4 + i] = f2bf(fmaxf(v1, 0.f));
        }
        afr[mt][ks] = au.v;
      }
    }
  }

  // prologue: stage regs for pass 0 (pass = 32 cols = 2048 uint4; 4/thread)
  const uint4* __restrict__ gsrc = (const uint4*)g_w2t;
  uint4 rg0, rg1, rg2, rg3;
  {
    const uint4* s = gsrc + tid;
    rg0 = s[0*512]; rg1 = s[1*512]; rg2 = s[2*512]; rg3 = s[3*512];
  }

  float rs[2][4] = {{0.f,0.f,0.f,0.f},{0.f,0.f,0.f,0.f}};

  #pragma unroll 1
  for (int p = 0; p < 16; ++p){
    {
      uint4* bw = (uint4*)buf[p & 1] + tid;
      bw[0*512] = rg0; bw[1*512] = rg1; bw[2*512] = rg2; bw[3*512] = rg3;
    }
    __syncthreads();               // write visible; dbuf makes this the ONLY barrier
    if (p < 15){
      const uint4* s = gsrc + (p + 1) * 2048 + tid;
      rg0 = s[0*512]; rg1 = s[1*512]; rg2 = s[2*512]; rg3 = s[3*512];
    }
    float b2v[2], w3v[2];
    #pragma unroll
    for (int nt = 0; nt < 2; ++nt){
      const int n = p*32 + nt*16 + c16;
      b2v[nt] = b2[n];
      w3v[nt] = W3[n];
    }

    const unsigned short* __restrict__ bb = buf[p & 1];
    f32x4 acc[2][2];
    #pragma unroll
    for (int nt = 0; nt < 2; ++nt){
      f32x4 z = {0.f,0.f,0.f,0.f};
      acc[0][nt] = z; acc[1][nt] = z;
    }
    #pragma unroll
    for (int ks = 0; ks < 16; ++ks){
      #pragma unroll
      for (int nt = 0; nt < 2; ++nt){
        const int nl = nt*16 + c16;                    // local col 0..31
        const bf16x8 bfr =
          *(const bf16x8*)&bb[(nl << 9) | ((ks*32 + kb) ^ ((nl & 7) << 3))];
        acc[0][nt] = __builtin_amdgcn_mfma_f32_16x16x32_bf16(afr[0][ks], bfr, acc[0][nt], 0, 0, 0);
        acc[1][nt] = __builtin_amdgcn_mfma_f32_16x16x32_bf16(afr[1][ks], bfr, acc[1][nt], 0, 0, 0);
      }
    }
    #pragma unroll
    for (int nt = 0; nt < 2; ++nt){
      #pragma unroll
      for (int mt = 0; mt < 2; ++mt)
        #pragma unroll
        for (int r = 0; r < 4; ++r)
          rs[mt][r] += fmaxf(acc[mt][nt][r] + b2v[nt], 0.f) * w3v[nt];
    }
  }

  // reduce across the 16 lanes (c16 bits) sharing the same C-rows
  #pragma unroll
  for (int mt = 0; mt < 2; ++mt){
    #pragma unroll
    for (int r = 0; r < 4; ++r){
      rs[mt][r] += __shfl_xor(rs[mt][r], 1);
      rs[mt][r] += __shfl_xor(rs[mt][r], 2);
      rs[mt][r] += __shfl_xor(rs[mt][r], 4);
      rs[mt][r] += __shfl_xor(rs[mt][r], 8);
    }
  }
  if (c16 == 0){
    const float bv = b3[0];
    #pragma unroll
    for (int mt = 0; mt < 2; ++mt){
      const int row = m0 + mt*16 + (l >> 4) * 4;
      #pragma unroll
      for (int r = 0; r < 4; ++r)
        out[3*BT_ + row + r] = rs[mt][r] + bv;
    }
  }
}

extern "C" void kernel_launch(void* const* d_in, const int* in_sizes, int n_in,
                              void* d_out, int out_size, void* d_ws, size_t ws_size,
                              hipStream_t stream){
  LstmArgs A;
  for (int i = 0; i < 3; ++i){
    A.x[i]    = (const float*)d_in[i];
    A.Wih[i]  = (const float*)d_in[3 + i*5 + 0];
    A.Whh[i]  = (const float*)d_in[3 + i*5 + 1];
    A.bias[i] = (const float*)d_in[3 + i*5 + 2];
    A.hw[i]   = (const float*)d_in[3 + i*5 + 3];
    A.hb[i]   = (const float*)d_in[3 + i*5 + 4];
  }
  A.out = (float*)d_out;

  prep_all<<<dim3(2048), dim3(256), 0, stream>>>(A, (const float*)d_in[20]);
  lstm_mfma_kernel<<<dim3(192), dim3(512), 0, stream>>>(A);
  mlp_kernel<<<dim3(512), dim3(512), 0, stream>>>((const float*)d_out,
      (const float*)d_in[18], (const float*)d_in[19],
      (const float*)d_in[21], (const float*)d_in[22], (const float*)d_in[23],
      (float*)d_out);
}